// Round 7
// baseline (38.125 us; speedup 1.0000x reference)
//
#include <hip/hip_runtime.h>
#include <math.h>

#define NPAR 130048
#define EPSF 1e-5f

typedef _Float16 hfp;
typedef _Float16 h2x __attribute__((ext_vector_type(2)));
typedef _Float16 h4x __attribute__((ext_vector_type(4)));
typedef float    f4x __attribute__((ext_vector_type(4)));

// ---- strides (chosen: %4==0 for 8B-aligned b64 frags; (STR/2)%32 spreads banks) ----
#define WSTRW 156      // w_s row stride (f32)
#define BSTR  164      // beta row stride (f32)
#define VSTR2 172      // vposT row stride (halves)
#define ATSTR 172      // att row stride (halves)
#define WOSTR 76       // Wo / L1 row stride (halves)
#define L2STRH 108     // L2 row stride (halves)
#define OSTR  76       // O / h1 row stride (halves)
#define RSTR  108      // r row stride (halves)

// ---- LDS float offsets ----
#define OFF_VPOST 0        // f16 [64][172]  = 5504 floats
#define OFF_WO    5504     // f16 [64][76]   = 2432
#define OFF_L1    7936     // f16 [96][76]   = 3648
#define OFF_L2    11584    // f16 [64][108]  = 3456
#define OFF_BETA  15040    // f32 [4][164]   = 656
#define OFF_SM    15696    // f32 smalls     = 704
#define SM_CT   0
#define SM_BO   64
#define SM_B1   128
#define SM_B2   224
#define SM_LN1W 288
#define SM_LN1B 352
#define SM_LN2W 416
#define SM_LN2B 480
#define SM_ALPH 544
#define SM_GAM  548
#define SM_MB   552
#define STAGE_FLOATS 16400          // staged contiguously from ws
#define OFF_W    16400              // f32 [16][156] = 2496
#define OFF_ATT  18896              // f16 [64][172] = 5504
#define OFF_O    24400              // f16 [16][76]  = 608
#define OFF_H1   25008              // 608
#define OFF_R    25616              // f16 [16][108] = 864
#define OFF_INVS 26480              // f32 [64]
#define LDS_FLOATS 26560            // 106,240 B

#define WAVE_SYNC() asm volatile("s_waitcnt lgkmcnt(0)" ::: "memory")

template<int C>
__device__ __forceinline__ float dppf(float x) {
    return __int_as_float(__builtin_amdgcn_update_dpp(0, __float_as_int(x), C, 0xf, 0xf, false));
}
__device__ __forceinline__ float rowsum16(float x) {  // full sum within each 16-lane row
    x += dppf<0x128>(x); x += dppf<0x124>(x); x += dppf<0x122>(x); x += dppf<0x121>(x);
    return x;
}
__device__ __forceinline__ float rowmax16(float x) {
    x = fmaxf(x, dppf<0x128>(x)); x = fmaxf(x, dppf<0x124>(x));
    x = fmaxf(x, dppf<0x122>(x)); x = fmaxf(x, dppf<0x121>(x));
    return x;
}
__device__ __forceinline__ unsigned packh2(float a, float b) {
    union { h2x h; unsigned u; } cv;
    cv.h.x = (hfp)a; cv.h.y = (hfp)b;
    return cv.u;
}

// ===================== k_pre: build the packed staging block in ws =====================
// blocks 0..144: vposT col j (f16) + beta[h][j]
// block 145: vcls/uv -> vposT cols 156/157, zero pads, alpha/gamma
// block 146: smalls; 147: Wo->f16; 148: L1->f16; 149: L2->f16
__global__ __launch_bounds__(64) void k_pre(const float* __restrict__ pe,
                                            const float* __restrict__ ct,
                                            const float* __restrict__ W,
                                            const float* __restrict__ bq,
                                            const float* __restrict__ Wo,
                                            const float* __restrict__ bo,
                                            const float* __restrict__ L1w,
                                            const float* __restrict__ b1,
                                            const float* __restrict__ L2w,
                                            const float* __restrict__ b2,
                                            const float* __restrict__ ln1w,
                                            const float* __restrict__ ln1b,
                                            const float* __restrict__ ln2w,
                                            const float* __restrict__ ln2b,
                                            float* __restrict__ ws)
{
    const int j = blockIdx.x;
    const int o = threadIdx.x;
    hfp* wsh = (hfp*)ws;

    if (j < 145) {
        const float4* wq4 = (const float4*)(W + o*64);
        const float4* wk4 = (const float4*)(W + (64 + o)*64);
        const float4* wv4 = (const float4*)(W + (128 + o)*64);
        const float4* p4  = (const float4*)(pe + j*64);
        float sk = bq[64 + o], sv = bq[128 + o], sq = bq[o];
        #pragma unroll
        for (int e = 0; e < 16; ++e) {
            float4 k4 = wk4[e], v4 = wv4[e], q4 = wq4[e], pp = p4[e];
            float4 cc = ((const float4*)ct)[e];
            sk += k4.x*pp.x + k4.y*pp.y + k4.z*pp.z + k4.w*pp.w;
            sv += v4.x*pp.x + v4.y*pp.y + v4.z*pp.z + v4.w*pp.w;
            sq += q4.x*cc.x + q4.y*cc.y + q4.z*cc.z + q4.w*cc.w;
        }
        wsh[o*VSTR2 + j] = (hfp)sv;                 // vposT (transposed, f16)
        float r = sq * sk;
        #pragma unroll
        for (int off = 1; off < 16; off <<= 1) r += __shfl_xor(r, off);
        if ((o & 15) == 0) ws[OFF_BETA + (o >> 4)*BSTR + j] = r;
    } else if (j == 145) {
        const float4* wq4 = (const float4*)(W + o*64);
        const float4* wk4 = (const float4*)(W + (64 + o)*64);
        const float4* wv4 = (const float4*)(W + (128 + o)*64);
        float sq = bq[o], sk = bq[64 + o], sv = bq[128 + o], suk = 0.f, suv = 0.f;
        #pragma unroll
        for (int e = 0; e < 16; ++e) {
            float4 k4 = wk4[e], v4 = wv4[e], q4 = wq4[e];
            float4 cc = ((const float4*)ct)[e];
            sq += q4.x*cc.x + q4.y*cc.y + q4.z*cc.z + q4.w*cc.w;
            sk += k4.x*cc.x + k4.y*cc.y + k4.z*cc.z + k4.w*cc.w;
            sv += v4.x*cc.x + v4.y*cc.y + v4.z*cc.z + v4.w*cc.w;
            suk += k4.x + k4.y + k4.z + k4.w;
            suv += v4.x + v4.y + v4.z + v4.w;
        }
        // vcls -> col 156, uv -> col 157
        wsh[o*VSTR2 + 156] = (hfp)sv;
        wsh[o*VSTR2 + 157] = (hfp)suv;
        // zero pad cols 145..155 and 158..159
        #pragma unroll
        for (int c = 145; c < 156; ++c) wsh[o*VSTR2 + c] = (hfp)0.f;
        wsh[o*VSTR2 + 158] = (hfp)0.f;
        wsh[o*VSTR2 + 159] = (hfp)0.f;
        float a = sq * suk, g = sq * sk;
        #pragma unroll
        for (int off = 1; off < 16; off <<= 1) {
            a += __shfl_xor(a, off);
            g += __shfl_xor(g, off);
        }
        if ((o & 15) == 0) {
            ws[OFF_SM + SM_ALPH + (o >> 4)] = a;
            ws[OFF_SM + SM_GAM  + (o >> 4)] = g;
        }
    } else if (j == 146) {
        ws[OFF_SM + SM_CT   + o] = ct[o];
        ws[OFF_SM + SM_BO   + o] = bo[o];
        ws[OFF_SM + SM_B2   + o] = b2[o];
        ws[OFF_SM + SM_LN1W + o] = ln1w[o];
        ws[OFF_SM + SM_LN1B + o] = ln1b[o];
        ws[OFF_SM + SM_LN2W + o] = ln2w[o];
        ws[OFF_SM + SM_LN2B + o] = ln2b[o];
        ws[OFF_SM + SM_B1   + o] = b1[o];
        if (o < 32) ws[OFF_SM + SM_B1 + 64 + o] = b1[64 + o];
    } else if (j == 147) {
        for (int idx = o; idx < 4096; idx += 64)
            wsh[OFF_WO*2 + (idx >> 6)*WOSTR + (idx & 63)] = (hfp)Wo[idx];
    } else if (j == 148) {
        for (int idx = o; idx < 6144; idx += 64)
            wsh[OFF_L1*2 + (idx >> 6)*WOSTR + (idx & 63)] = (hfp)L1w[idx];
    } else {
        for (int idx = o; idx < 6144; idx += 64) {
            int r = idx / 96, c = idx - r*96;
            wsh[OFF_L2*2 + r*L2STRH + c] = (hfp)L2w[idx];
        }
    }
}

// ===================== k_main: one wave per 16 consecutive sequences =====================
template<int L>
__device__ __forceinline__ void run16(const float* __restrict__ x,
                                      float* __restrict__ lds,
                                      float* __restrict__ out,
                                      int b, int k0, int start, int kno, int kgo, int l)
{
    const hfp* ldsh = (const hfp*)lds;
    const int e16 = l & 15;
    const int g4  = (l >> 4) * 4;

    // ---- stage 16 consecutive sequences' scalar params (contiguous 16*L floats) ----
    const float* xw = x + (size_t)b*NPAR + start + (size_t)k0*L;
    float wmax = 0.f;
    #pragma unroll
    for (int i = l; i < 4*L; i += 64) {          // 4L float4s
        f4x v = *(const f4x*)(xw + 4*i);
        int m = (4*i) / L, jj = (4*i) % L;
        *(f4x*)(lds + OFF_W + m*WSTRW + jj) = v;
        wmax = fmaxf(wmax, fmaxf(fmaxf(fabsf(v.x), fabsf(v.y)), fmaxf(fabsf(v.z), fabsf(v.w))));
    }
    if (l < 16) {
        float bw = x[(size_t)b*NPAR + start + (size_t)kno*L + k0 + l];
        lds[OFF_W + l*WSTRW + L] = bw;
        wmax = fmaxf(wmax, fabsf(bw));
    }
    // global |w| max across wave (safe bound; per-seq not needed)
    wmax = rowmax16(wmax);
    wmax = fmaxf(wmax, __shfl_xor(wmax, 16));
    wmax = fmaxf(wmax, __shfl_xor(wmax, 32));
    WAVE_SYNC();

    // ---- maxbeta[h] ----
    {
        int hh = l >> 4;
        float mb = -1e30f;
        #pragma unroll
        for (int t = 0; t < 10; ++t) {
            int jj = e16 + 16*t;
            if (jj < 145) mb = fmaxf(mb, lds[OFF_BETA + hh*BSTR + jj]);
        }
        mb = rowmax16(mb);
        if (e16 == 0) lds[OFF_SM + SM_MB + hh] = mb;
    }
    WAVE_SYNC();

    // ---- softmax: lane = (seq m = l>>2, head h = l&3), fully lane-local ----
    {
        const int m = l >> 2, h = l & 3;
        const float alpha = lds[OFF_SM + SM_ALPH + h];
        const float gam   = lds[OFF_SM + SM_GAM  + h];
        const float mb    = lds[OFF_SM + SM_MB   + h];
        float M = 0.25f * (fabsf(alpha)*wmax + mb);
        M = fmaxf(M, 0.25f * gam);
        const float* wr = lds + OFF_W + m*WSTRW;
        const float* br = lds + OFF_BETA + h*BSTR;
        unsigned* arow32 = (unsigned*)(lds + OFF_ATT) + (m*4 + h)*(ATSTR/2);

        float S = 0.f, WS = 0.f;
        constexpr int NCH = L / 4;               // full chunks (L%4==0), remainder j=L
        #pragma unroll
        for (int c = 0; c < NCH; ++c) {
            f4x wv = *(const f4x*)(wr + 4*c);
            f4x bv = *(const f4x*)(br + 4*c);
            float p0 = __expf(fmaf(alpha, wv.x, bv.x)*0.25f - M);
            float p1 = __expf(fmaf(alpha, wv.y, bv.y)*0.25f - M);
            float p2 = __expf(fmaf(alpha, wv.z, bv.z)*0.25f - M);
            float p3 = __expf(fmaf(alpha, wv.w, bv.w)*0.25f - M);
            S  += (p0 + p1) + (p2 + p3);
            WS += (p0*wv.x + p1*wv.y) + (p2*wv.z + p3*wv.w);
            uint2 u; u.x = packh2(p0, p1); u.y = packh2(p2, p3);
            *(uint2*)(arow32 + 2*c) = u;
        }
        float wL = wr[L];
        float pL = __expf(fmaf(alpha, wL, br[L])*0.25f - M);
        S += pL; WS += pL*wL;
        arow32[L/2] = packh2(pL, 0.f);
        #pragma unroll
        for (int dq = L/2 + 1; dq < 78; ++dq) arow32[dq] = 0u;
        float pc = __expf(0.25f*gam - M);        // CLS
        S += pc;
        arow32[78] = packh2(pc, WS);             // cols 156 (a0), 157 (wsum, unnorm)
        arow32[79] = 0u;
        lds[OFF_INVS + l] = 1.f / S;
    }
    WAVE_SYNC();

    // ---- V-step: 4 head-GEMMs [16 x 160] @ [160 x 16] via mfma 16x16x16 f16 ----
    {
        const hfp* attb = ldsh + OFF_ATT*2;
        f4x vacc[4];
        #pragma unroll
        for (int hh = 0; hh < 4; ++hh) vacc[hh] = (f4x){0.f,0.f,0.f,0.f};
        #pragma unroll
        for (int kt = 0; kt < 10; ++kt) {
            #pragma unroll
            for (int hh = 0; hh < 4; ++hh) {
                h4x a = *(const h4x*)(attb + (e16*4 + hh)*ATSTR + kt*16 + g4);
                h4x bf = *(const h4x*)(ldsh + (16*hh + e16)*VSTR2 + kt*16 + g4);
                vacc[hh] = __builtin_amdgcn_mfma_f32_16x16x16f16(a, bf, vacc[hh], 0, 0, 0);
            }
        }
        hfp* Ob = (hfp*)(lds + OFF_O);
        #pragma unroll
        for (int hh = 0; hh < 4; ++hh) {
            #pragma unroll
            for (int r = 0; r < 4; ++r) {
                float sc = lds[OFF_INVS + (g4 + r)*4 + hh];
                Ob[(g4 + r)*OSTR + 16*hh + e16] = (hfp)(vacc[hh][r] * sc);
            }
        }
    }
    WAVE_SYNC();

    // ---- out-proj GEMM + residual(cls) + LN1 (in-register, DPP) ----
    float h1v[4][4];                              // [tile][r], post-LN1
    {
        const hfp* Ob = ldsh + OFF_O*2;
        const hfp* Wob = ldsh + OFF_WO*2;
        h4x afr[4];
        #pragma unroll
        for (int kt = 0; kt < 4; ++kt) afr[kt] = *(const h4x*)(Ob + e16*OSTR + kt*16 + g4);
        f4x pacc[4];
        #pragma unroll
        for (int tn = 0; tn < 4; ++tn) pacc[tn] = (f4x){0.f,0.f,0.f,0.f};
        #pragma unroll
        for (int kt = 0; kt < 4; ++kt)
            #pragma unroll
            for (int tn = 0; tn < 4; ++tn) {
                h4x bf = *(const h4x*)(Wob + (16*tn + e16)*WOSTR + kt*16 + g4);
                pacc[tn] = __builtin_amdgcn_mfma_f32_16x16x16f16(afr[kt], bf, pacc[tn], 0, 0, 0);
            }
        float mu[4] = {0.f,0.f,0.f,0.f};
        #pragma unroll
        for (int tn = 0; tn < 4; ++tn) {
            int n = e16 + 16*tn;
            float add = lds[OFF_SM + SM_BO + n] + lds[OFF_SM + SM_CT + n];
            #pragma unroll
            for (int r = 0; r < 4; ++r) { h1v[tn][r] = pacc[tn][r] + add; mu[r] += h1v[tn][r]; }
        }
        float rs[4];
        #pragma unroll
        for (int r = 0; r < 4; ++r) mu[r] = rowsum16(mu[r]) * (1.f/64.f);
        float vr[4] = {0.f,0.f,0.f,0.f};
        #pragma unroll
        for (int tn = 0; tn < 4; ++tn)
            #pragma unroll
            for (int r = 0; r < 4; ++r) { float d = h1v[tn][r] - mu[r]; h1v[tn][r] = d; vr[r] += d*d; }
        #pragma unroll
        for (int r = 0; r < 4; ++r) rs[r] = rsqrtf(rowsum16(vr[r])*(1.f/64.f) + EPSF);
        hfp* H1b = (hfp*)(lds + OFF_H1);
        #pragma unroll
        for (int tn = 0; tn < 4; ++tn) {
            int n = e16 + 16*tn;
            float lw = lds[OFF_SM + SM_LN1W + n], lb = lds[OFF_SM + SM_LN1B + n];
            #pragma unroll
            for (int r = 0; r < 4; ++r) {
                float hv = h1v[tn][r]*rs[r]*lw + lb;
                h1v[tn][r] = hv;
                H1b[(g4 + r)*OSTR + n] = (hfp)hv;
            }
        }
    }
    WAVE_SYNC();

    // ---- FF1 GEMM [16x64]@[64x96] + relu ----
    {
        const hfp* H1b = ldsh + OFF_H1*2;
        const hfp* L1b = ldsh + OFF_L1*2;
        h4x af1[4];
        #pragma unroll
        for (int kt = 0; kt < 4; ++kt) af1[kt] = *(const h4x*)(H1b + e16*OSTR + kt*16 + g4);
        f4x racc[6];
        #pragma unroll
        for (int tn = 0; tn < 6; ++tn) racc[tn] = (f4x){0.f,0.f,0.f,0.f};
        #pragma unroll
        for (int kt = 0; kt < 4; ++kt)
            #pragma unroll
            for (int tn = 0; tn < 6; ++tn) {
                h4x bf = *(const h4x*)(L1b + (16*tn + e16)*WOSTR + kt*16 + g4);
                racc[tn] = __builtin_amdgcn_mfma_f32_16x16x16f16(af1[kt], bf, racc[tn], 0, 0, 0);
            }
        hfp* Rb = (hfp*)(lds + OFF_R);
        #pragma unroll
        for (int tn = 0; tn < 6; ++tn) {
            int n = e16 + 16*tn;
            float bb = lds[OFF_SM + SM_B1 + n];
            #pragma unroll
            for (int r = 0; r < 4; ++r)
                Rb[(g4 + r)*RSTR + n] = (hfp)fmaxf(racc[tn][r] + bb, 0.f);
        }
    }
    WAVE_SYNC();

    // ---- FF2 GEMM [16x96]@[96x64] + residual + LN2 + store ----
    {
        const hfp* Rb = ldsh + OFF_R*2;
        const hfp* L2b = ldsh + OFF_L2*2;
        h4x af2[6];
        #pragma unroll
        for (int kt = 0; kt < 6; ++kt) af2[kt] = *(const h4x*)(Rb + e16*RSTR + kt*16 + g4);
        f4x yacc[4];
        #pragma unroll
        for (int tn = 0; tn < 4; ++tn) yacc[tn] = (f4x){0.f,0.f,0.f,0.f};
        #pragma unroll
        for (int kt = 0; kt < 6; ++kt)
            #pragma unroll
            for (int tn = 0; tn < 4; ++tn) {
                h4x bf = *(const h4x*)(L2b + (16*tn + e16)*L2STRH + kt*16 + g4);
                yacc[tn] = __builtin_amdgcn_mfma_f32_16x16x16f16(af2[kt], bf, yacc[tn], 0, 0, 0);
            }
        float yv[4][4];
        float mu[4] = {0.f,0.f,0.f,0.f};
        #pragma unroll
        for (int tn = 0; tn < 4; ++tn) {
            int n = e16 + 16*tn;
            float bb = lds[OFF_SM + SM_B2 + n];
            #pragma unroll
            for (int r = 0; r < 4; ++r) { yv[tn][r] = yacc[tn][r] + bb + h1v[tn][r]; mu[r] += yv[tn][r]; }
        }
        float rs[4];
        #pragma unroll
        for (int r = 0; r < 4; ++r) mu[r] = rowsum16(mu[r]) * (1.f/64.f);
        float vr[4] = {0.f,0.f,0.f,0.f};
        #pragma unroll
        for (int tn = 0; tn < 4; ++tn)
            #pragma unroll
            for (int r = 0; r < 4; ++r) { float d = yv[tn][r] - mu[r]; yv[tn][r] = d; vr[r] += d*d; }
        #pragma unroll
        for (int r = 0; r < 4; ++r) rs[r] = rsqrtf(rowsum16(vr[r])*(1.f/64.f) + EPSF);
        float* ob = out + ((size_t)b*1024 + kgo + k0) * 128;
        #pragma unroll
        for (int tn = 0; tn < 4; ++tn) {
            int n = e16 + 16*tn;
            float lw = lds[OFF_SM + SM_LN2W + n], lb = lds[OFF_SM + SM_LN2B + n];
            #pragma unroll
            for (int r = 0; r < 4; ++r) {
                float y = yv[tn][r]*rs[r]*lw + lb;
                int mm = g4 + r;
                ob[mm*128 + n]      = y;
                ob[mm*128 + 64 + n] = y;    // tile (1,1,2)
            }
        }
    }
}

__global__ __launch_bounds__(64, 1) void k_main(const float* __restrict__ x,
                                                const float* __restrict__ ws,
                                                float* __restrict__ out)
{
    __shared__ float lds[LDS_FLOATS];
    const int l = threadIdx.x;
    const int w = blockIdx.x;

    // ---- stage shared block (linear copy, same layout as ws) ----
    {
        const f4x* src = (const f4x*)ws;
        f4x* dst = (f4x*)lds;
        for (int i = l; i < STAGE_FLOATS/4; i += 64) dst[i] = src[i];
    }

    if (w < 64) {
        int b = w >> 4, k0 = (w & 15) * 16;
        run16<72>(x, lds, out, b, k0, 0, 256, 0, l);
    } else if (w < 128) {
        int w2 = w - 64;
        int b = w2 >> 4, k0 = (w2 & 15) * 16;
        run16<144>(x, lds, out, b, k0, 18688, 256, 256, l);
    } else {
        int w3 = w - 128;
        int b = w3 >> 5, k0 = (w3 & 31) * 16;
        run16<144>(x, lds, out, b, k0, 55808, 512, 512, l);
    }
}

extern "C" void kernel_launch(void* const* d_in, const int* in_sizes, int n_in,
                              void* d_out, int out_size, void* d_ws, size_t ws_size,
                              hipStream_t stream) {
    const float* x    = (const float*)d_in[0];
    const float* pe   = (const float*)d_in[1];
    const float* ct   = (const float*)d_in[2];
    const float* Wq   = (const float*)d_in[3];
    const float* bq   = (const float*)d_in[4];
    const float* Wo   = (const float*)d_in[5];
    const float* bo   = (const float*)d_in[6];
    const float* L1w  = (const float*)d_in[7];
    const float* b1   = (const float*)d_in[8];
    const float* L2w  = (const float*)d_in[9];
    const float* b2   = (const float*)d_in[10];
    const float* ln1w = (const float*)d_in[11];
    const float* ln1b = (const float*)d_in[12];
    const float* ln2w = (const float*)d_in[13];
    const float* ln2b = (const float*)d_in[14];
    float* out = (float*)d_out;
    float* ws  = (float*)d_ws;

    k_pre <<<150, 64, 0, stream>>>(pe, ct, Wq, bq, Wo, bo, L1w, b1, L2w, b2,
                                   ln1w, ln1b, ln2w, ln2b, ws);
    k_main<<<256, 64, 0, stream>>>(x, ws, out);
}

// Round 8
// 19.843 us; speedup vs baseline: 1.9213x; 1.9213x over previous
//
#include <hip/hip_runtime.h>
#include <math.h>

#define NPAR 130048
#define EPSF 1e-5f

typedef _Float16 hfp;
typedef _Float16 h2x __attribute__((ext_vector_type(2)));
typedef _Float16 h4x __attribute__((ext_vector_type(4)));
typedef float    f4x __attribute__((ext_vector_type(4)));

// ---- strides ----
#define BSTR  164      // beta row stride (f32)
#define VSTR2 172      // vposT row stride (halves)
#define ATSTR 172      // att row stride (halves)
#define WOSTR 76       // Wo / L1 / O / H1 row stride (halves)
#define L2STRH 108     // L2 / R row stride (halves)

// ---- staged shared block (identical layout in ws and LDS; float offsets) ----
#define OFF_VPOST 0        // f16 [64][172]  = 5504 floats
#define OFF_WO    5504     // f16 [64][76]   = 2432
#define OFF_L1    7936     // f16 [96][76]   = 3648
#define OFF_L2    11584    // f16 [64][108]  = 3456
#define OFF_BETA  15040    // f32 [4][164]   = 656
#define OFF_SM    15696    // f32 smalls     = 704
#define SM_CT   0
#define SM_BO   64
#define SM_B1   128
#define SM_B2   224
#define SM_LN1W 288
#define SM_LN1B 352
#define SM_LN2W 416
#define SM_LN2B 480
#define SM_ALPH 544
#define SM_GAM  548
#define STAGE_FLOATS 16400
// ---- dynamic region ----
#define OFF_W    16400     // f32 [16][L] packed (max 16*144 = 2304)
#define OFF_WB   18704     // f32 [16] bias-token params
#define OFF_ATT  18720     // f16 [64][172] = 5504 floats
#define OFF_INVS 24224     // f32 [64]
#define OFF_O    24288     // f16 [16][76] = 608
#define OFF_H1   24896     // f16 [16][76] = 608
#define OFF_R    25504     // f16 [16][108] = 864
#define OFF_PRE  26368     // f32 [16][68] = 1088
#define OFF_RED  27456     // f32 [16]
#define LDS_FLOATS 27472   // 109,888 B

template<int C>
__device__ __forceinline__ float dppf(float x) {
    return __int_as_float(__builtin_amdgcn_update_dpp(0, __float_as_int(x), C, 0xf, 0xf, false));
}
__device__ __forceinline__ float rowsum16(float x) {  // sum within each 16-lane row
    x += dppf<0x128>(x); x += dppf<0x124>(x); x += dppf<0x122>(x); x += dppf<0x121>(x);
    return x;
}
__device__ __forceinline__ unsigned packh2(float a, float b) {
    union { h2x h; unsigned u; } cv;
    cv.h.x = (hfp)a; cv.h.y = (hfp)b;
    return cv.u;
}

// ===================== k_pre: build the packed staging block in ws (same as R7) =====================
__global__ __launch_bounds__(64) void k_pre(const float* __restrict__ pe,
                                            const float* __restrict__ ct,
                                            const float* __restrict__ W,
                                            const float* __restrict__ bq,
                                            const float* __restrict__ Wo,
                                            const float* __restrict__ bo,
                                            const float* __restrict__ L1w,
                                            const float* __restrict__ b1,
                                            const float* __restrict__ L2w,
                                            const float* __restrict__ b2,
                                            const float* __restrict__ ln1w,
                                            const float* __restrict__ ln1b,
                                            const float* __restrict__ ln2w,
                                            const float* __restrict__ ln2b,
                                            float* __restrict__ ws)
{
    const int j = blockIdx.x;
    const int o = threadIdx.x;
    hfp* wsh = (hfp*)ws;

    if (j < 145) {
        const float4* wq4 = (const float4*)(W + o*64);
        const float4* wk4 = (const float4*)(W + (64 + o)*64);
        const float4* wv4 = (const float4*)(W + (128 + o)*64);
        const float4* p4  = (const float4*)(pe + j*64);
        float sk = bq[64 + o], sv = bq[128 + o], sq = bq[o];
        #pragma unroll
        for (int e = 0; e < 16; ++e) {
            float4 k4 = wk4[e], v4 = wv4[e], q4 = wq4[e], pp = p4[e];
            float4 cc = ((const float4*)ct)[e];
            sk += k4.x*pp.x + k4.y*pp.y + k4.z*pp.z + k4.w*pp.w;
            sv += v4.x*pp.x + v4.y*pp.y + v4.z*pp.z + v4.w*pp.w;
            sq += q4.x*cc.x + q4.y*cc.y + q4.z*cc.z + q4.w*cc.w;
        }
        wsh[o*VSTR2 + j] = (hfp)sv;
        float r = sq * sk;
        #pragma unroll
        for (int off = 1; off < 16; off <<= 1) r += __shfl_xor(r, off);
        if ((o & 15) == 0) ws[OFF_BETA + (o >> 4)*BSTR + j] = r;
    } else if (j == 145) {
        const float4* wq4 = (const float4*)(W + o*64);
        const float4* wk4 = (const float4*)(W + (64 + o)*64);
        const float4* wv4 = (const float4*)(W + (128 + o)*64);
        float sq = bq[o], sk = bq[64 + o], sv = bq[128 + o], suk = 0.f, suv = 0.f;
        #pragma unroll
        for (int e = 0; e < 16; ++e) {
            float4 k4 = wk4[e], v4 = wv4[e], q4 = wq4[e];
            float4 cc = ((const float4*)ct)[e];
            sq += q4.x*cc.x + q4.y*cc.y + q4.z*cc.z + q4.w*cc.w;
            sk += k4.x*cc.x + k4.y*cc.y + k4.z*cc.z + k4.w*cc.w;
            sv += v4.x*cc.x + v4.y*cc.y + v4.z*cc.z + v4.w*cc.w;
            suk += k4.x + k4.y + k4.z + k4.w;
            suv += v4.x + v4.y + v4.z + v4.w;
        }
        wsh[o*VSTR2 + 156] = (hfp)sv;     // vcls
        wsh[o*VSTR2 + 157] = (hfp)suv;    // uv
        #pragma unroll
        for (int c = 145; c < 156; ++c) wsh[o*VSTR2 + c] = (hfp)0.f;
        wsh[o*VSTR2 + 158] = (hfp)0.f;
        wsh[o*VSTR2 + 159] = (hfp)0.f;
        float a = sq * suk, g = sq * sk;
        #pragma unroll
        for (int off = 1; off < 16; off <<= 1) {
            a += __shfl_xor(a, off);
            g += __shfl_xor(g, off);
        }
        if ((o & 15) == 0) {
            ws[OFF_SM + SM_ALPH + (o >> 4)] = a;
            ws[OFF_SM + SM_GAM  + (o >> 4)] = g;
        }
    } else if (j == 146) {
        ws[OFF_SM + SM_CT   + o] = ct[o];
        ws[OFF_SM + SM_BO   + o] = bo[o];
        ws[OFF_SM + SM_B2   + o] = b2[o];
        ws[OFF_SM + SM_LN1W + o] = ln1w[o];
        ws[OFF_SM + SM_LN1B + o] = ln1b[o];
        ws[OFF_SM + SM_LN2W + o] = ln2w[o];
        ws[OFF_SM + SM_LN2B + o] = ln2b[o];
        ws[OFF_SM + SM_B1   + o] = b1[o];
        if (o < 32) ws[OFF_SM + SM_B1 + 64 + o] = b1[64 + o];
    } else if (j == 147) {
        for (int idx = o; idx < 4096; idx += 64)
            wsh[OFF_WO*2 + (idx >> 6)*WOSTR + (idx & 63)] = (hfp)Wo[idx];
    } else if (j == 148) {
        for (int idx = o; idx < 6144; idx += 64)
            wsh[OFF_L1*2 + (idx >> 6)*WOSTR + (idx & 63)] = (hfp)L1w[idx];
    } else {
        for (int idx = o; idx < 6144; idx += 64) {
            int r = idx / 96, c = idx - r*96;
            wsh[OFF_L2*2 + r*L2STRH + c] = (hfp)L2w[idx];
        }
    }
}

// ===================== k_main: 256 thr = 4 waves cooperate on one 16-seq group =====================
template<int L>
__device__ __forceinline__ void run_group(const float* __restrict__ x,
                                          float* __restrict__ lds,
                                          float* __restrict__ out,
                                          int b, int k0, int start, int kno, int kgo)
{
    const int tid  = threadIdx.x;
    const int wave = tid >> 6;
    const int lane = tid & 63;
    const int e16  = lane & 15;
    const int g4   = (lane >> 4) * 4;
    const hfp* ldsh = (const hfp*)lds;
    const float* sm = lds + OFF_SM;

    // ---- stage x: 16*L contiguous floats + 16 bias params ----
    {
        const f4x* src = (const f4x*)(x + (size_t)b*NPAR + start + (size_t)k0*L);
        f4x* dst = (f4x*)(lds + OFF_W);
        #pragma unroll
        for (int c = 0; c < (4*L + 255)/256; ++c) {
            int i4 = c*256 + tid;
            if (i4 < 4*L) dst[i4] = src[i4];
        }
        if (tid < 16) lds[OFF_WB + tid] = x[(size_t)b*NPAR + start + (size_t)kno*L + k0 + tid];
    }
    __syncthreads();   // covers shared-block staging (caller) + x staging

    // ---- wmax (block) + maxbeta per head ----
    {
        float wm = 0.f;
        for (int i = tid; i < 16*L; i += 256) wm = fmaxf(wm, fabsf(lds[OFF_W + i]));
        if (tid < 16) wm = fmaxf(wm, fabsf(lds[OFF_WB + tid]));
        #pragma unroll
        for (int off = 1; off < 64; off <<= 1) wm = fmaxf(wm, __shfl_xor(wm, off));
        if (lane == 0) lds[OFF_RED + wave] = wm;
        float mb = -1e30f;
        for (int j = lane; j < 145; j += 64) mb = fmaxf(mb, lds[OFF_BETA + wave*BSTR + j]);
        #pragma unroll
        for (int off = 1; off < 64; off <<= 1) mb = fmaxf(mb, __shfl_xor(mb, off));
        if (lane == 0) lds[OFF_RED + 8 + wave] = mb;
    }
    __syncthreads();

    // ---- softmax: 64 rows (m,h) x 4 segments, all 256 lanes ----
    {
        const float wmax = fmaxf(fmaxf(lds[OFF_RED+0], lds[OFF_RED+1]),
                                 fmaxf(lds[OFF_RED+2], lds[OFF_RED+3]));
        const int r = tid >> 2;          // m*4 + h
        const int m = r >> 2, h = r & 3, q = tid & 3;
        const float alpha = sm[SM_ALPH + h];
        const float gam   = sm[SM_GAM  + h];
        const float mbh   = lds[OFF_RED + 8 + h];
        const float M = fmaxf(0.25f*(fabsf(alpha)*wmax + mbh), 0.25f*gam);
        unsigned* arow32 = (unsigned*)(lds + OFF_ATT) + r*(ATSTR/2);
        const float* wr = lds + OFF_W + m*L;
        const float* br = lds + OFF_BETA + h*BSTR;
        float S = 0.f, WS = 0.f;
        #pragma unroll
        for (int t = 0; t < 10; ++t) {
            const int j0 = 16*t + 4*q;
            if (16*t + 15 < L || j0 + 3 < L) {          // full chunk
                f4x wv = *(const f4x*)(wr + j0);
                f4x bv = *(const f4x*)(br + j0);
                float p0 = __expf(fmaf(alpha, wv.x, bv.x)*0.25f - M);
                float p1 = __expf(fmaf(alpha, wv.y, bv.y)*0.25f - M);
                float p2 = __expf(fmaf(alpha, wv.z, bv.z)*0.25f - M);
                float p3 = __expf(fmaf(alpha, wv.w, bv.w)*0.25f - M);
                S  += (p0 + p1) + (p2 + p3);
                WS += (p0*wv.x + p1*wv.y) + (p2*wv.z + p3*wv.w);
                uint2 u; u.x = packh2(p0, p1); u.y = packh2(p2, p3);
                *(uint2*)(arow32 + (j0 >> 1)) = u;
            } else if (j0 <= L) {                        // chunk containing bias token
                float pv4[4] = {0.f, 0.f, 0.f, 0.f};
                #pragma unroll
                for (int ee = 0; ee < 4; ++ee) {
                    int j = j0 + ee;
                    if (j <= L) {
                        float w = (j < L) ? wr[j] : lds[OFF_WB + m];
                        float p = __expf(fmaf(alpha, w, br[j])*0.25f - M);
                        S += p; WS += p*w; pv4[ee] = p;
                    }
                }
                uint2 u; u.x = packh2(pv4[0], pv4[1]); u.y = packh2(pv4[2], pv4[3]);
                *(uint2*)(arow32 + (j0 >> 1)) = u;
            } else if (j0 != 156) {                      // zero pad (156-chunk written below)
                uint2 z; z.x = 0u; z.y = 0u;
                *(uint2*)(arow32 + (j0 >> 1)) = z;
            }
        }
        S  += __shfl_xor(S, 1);  S  += __shfl_xor(S, 2);
        WS += __shfl_xor(WS, 1); WS += __shfl_xor(WS, 2);
        const float pc = __expf(0.25f*gam - M);          // CLS
        S += pc;
        if (q == 0) {
            lds[OFF_INVS + r] = 1.f / S;
            arow32[78] = packh2(pc, WS);                 // cols 156 (a0), 157 (wsum)
            arow32[79] = 0u;
        }
    }
    __syncthreads();

    // ---- V-step: wave = head; 10 mfma ----
    {
        const hfp* atth = ldsh + OFF_ATT*2;
        const int hh = wave;
        f4x vacc = (f4x){0.f,0.f,0.f,0.f};
        #pragma unroll
        for (int kt = 0; kt < 10; ++kt) {
            h4x a  = *(const h4x*)(atth + (e16*4 + hh)*ATSTR + kt*16 + g4);
            h4x bf = *(const h4x*)(ldsh + (16*hh + e16)*VSTR2 + kt*16 + g4);
            vacc = __builtin_amdgcn_mfma_f32_16x16x16f16(a, bf, vacc, 0, 0, 0);
        }
        hfp* Oh = (hfp*)(lds + OFF_O);
        #pragma unroll
        for (int rr = 0; rr < 4; ++rr) {
            float sc = lds[OFF_INVS + (g4 + rr)*4 + hh];
            Oh[(g4 + rr)*WOSTR + 16*hh + e16] = (hfp)(vacc[rr] * sc);
        }
    }
    __syncthreads();

    // ---- out-proj: wave = output 16-col tile; 4 mfma -> f32 pre ----
    {
        const hfp* Oh  = ldsh + OFF_O*2;
        const hfp* Woh = ldsh + OFF_WO*2;
        const int tn = wave;
        f4x pacc = (f4x){0.f,0.f,0.f,0.f};
        #pragma unroll
        for (int kt = 0; kt < 4; ++kt) {
            h4x a  = *(const h4x*)(Oh + e16*WOSTR + kt*16 + g4);
            h4x bf = *(const h4x*)(Woh + (16*tn + e16)*WOSTR + kt*16 + g4);
            pacc = __builtin_amdgcn_mfma_f32_16x16x16f16(a, bf, pacc, 0, 0, 0);
        }
        const int n = 16*tn + e16;
        const float add = sm[SM_BO + n] + sm[SM_CT + n];
        #pragma unroll
        for (int rr = 0; rr < 4; ++rr)
            lds[OFF_PRE + (g4 + rr)*68 + n] = pacc[rr] + add;
    }
    __syncthreads();

    // ---- LN1 (row-split: wave owns 4 rows) ----
    {
        const int m  = wave*4 + (lane >> 4);
        const int c0 = (lane & 15) * 4;
        f4x pv = *(const f4x*)(lds + OFF_PRE + m*68 + c0);
        float s = (pv.x + pv.y) + (pv.z + pv.w);
        float mu = rowsum16(s) * (1.f/64.f);
        f4x d; d.x = pv.x-mu; d.y = pv.y-mu; d.z = pv.z-mu; d.w = pv.w-mu;
        float v = (d.x*d.x + d.y*d.y) + (d.z*d.z + d.w*d.w);
        float rs = rsqrtf(rowsum16(v)*(1.f/64.f) + EPSF);
        f4x lw = *(const f4x*)(sm + SM_LN1W + c0);
        f4x lb = *(const f4x*)(sm + SM_LN1B + c0);
        h4x hv;
        hv.x = (hfp)(d.x*rs*lw.x + lb.x);
        hv.y = (hfp)(d.y*rs*lw.y + lb.y);
        hv.z = (hfp)(d.z*rs*lw.z + lb.z);
        hv.w = (hfp)(d.w*rs*lw.w + lb.w);
        *(h4x*)((hfp*)(lds + OFF_H1) + m*WOSTR + c0) = hv;
    }
    __syncthreads();

    // ---- FF1: waves cover 6 output tiles (0..5); relu -> R f16 ----
    {
        const hfp* H1h = ldsh + OFF_H1*2;
        const hfp* L1h = ldsh + OFF_L1*2;
        h4x af[4];
        #pragma unroll
        for (int kt = 0; kt < 4; ++kt) af[kt] = *(const h4x*)(H1h + e16*WOSTR + kt*16 + g4);
        hfp* Rh = (hfp*)(lds + OFF_R);
        #pragma unroll
        for (int u = 0; u < 2; ++u) {
            const int tt = wave + u*4;
            if (tt < 6) {
                f4x racc = (f4x){0.f,0.f,0.f,0.f};
                #pragma unroll
                for (int kt = 0; kt < 4; ++kt) {
                    h4x bf = *(const h4x*)(L1h + (16*tt + e16)*WOSTR + kt*16 + g4);
                    racc = __builtin_amdgcn_mfma_f32_16x16x16f16(af[kt], bf, racc, 0, 0, 0);
                }
                const int n = 16*tt + e16;
                const float bb = sm[SM_B1 + n];
                #pragma unroll
                for (int rr = 0; rr < 4; ++rr)
                    Rh[(g4 + rr)*L2STRH + n] = (hfp)fmaxf(racc[rr] + bb, 0.f);
            }
        }
    }
    __syncthreads();

    // ---- FF2: wave = output tile; 6 mfma -> f32 pre ----
    {
        const hfp* Rh2 = ldsh + OFF_R*2;
        const hfp* L2h = ldsh + OFF_L2*2;
        const int tn = wave;
        h4x af[6];
        #pragma unroll
        for (int kt = 0; kt < 6; ++kt) af[kt] = *(const h4x*)(Rh2 + e16*L2STRH + kt*16 + g4);
        f4x yacc = (f4x){0.f,0.f,0.f,0.f};
        #pragma unroll
        for (int kt = 0; kt < 6; ++kt) {
            h4x bf = *(const h4x*)(L2h + (16*tn + e16)*L2STRH + kt*16 + g4);
            yacc = __builtin_amdgcn_mfma_f32_16x16x16f16(af[kt], bf, yacc, 0, 0, 0);
        }
        const int n = 16*tn + e16;
        const float bb = sm[SM_B2 + n];
        #pragma unroll
        for (int rr = 0; rr < 4; ++rr)
            lds[OFF_PRE + (g4 + rr)*68 + n] = yacc[rr] + bb;
    }
    __syncthreads();

    // ---- LN2 + residual(h1) + store ----
    {
        const int m  = wave*4 + (lane >> 4);
        const int c0 = (lane & 15) * 4;
        f4x pv = *(const f4x*)(lds + OFF_PRE + m*68 + c0);
        h4x h1p = *(const h4x*)((const hfp*)(lds + OFF_H1) + m*WOSTR + c0);
        f4x tot;
        tot.x = pv.x + (float)h1p.x;
        tot.y = pv.y + (float)h1p.y;
        tot.z = pv.z + (float)h1p.z;
        tot.w = pv.w + (float)h1p.w;
        float s = (tot.x + tot.y) + (tot.z + tot.w);
        float mu = rowsum16(s) * (1.f/64.f);
        f4x d; d.x = tot.x-mu; d.y = tot.y-mu; d.z = tot.z-mu; d.w = tot.w-mu;
        float v = (d.x*d.x + d.y*d.y) + (d.z*d.z + d.w*d.w);
        float rs = rsqrtf(rowsum16(v)*(1.f/64.f) + EPSF);
        f4x lw = *(const f4x*)(sm + SM_LN2W + c0);
        f4x lb = *(const f4x*)(sm + SM_LN2B + c0);
        f4x y;
        y.x = d.x*rs*lw.x + lb.x;
        y.y = d.y*rs*lw.y + lb.y;
        y.z = d.z*rs*lw.z + lb.z;
        y.w = d.w*rs*lw.w + lb.w;
        float* ob = out + ((size_t)b*1024 + kgo + k0 + m)*128;
        *(f4x*)(ob + c0)      = y;
        *(f4x*)(ob + 64 + c0) = y;   // tile (1,1,2)
    }
}

__global__ __launch_bounds__(256, 1) void k_main(const float* __restrict__ x,
                                                 const float* __restrict__ ws,
                                                 float* __restrict__ out)
{
    __shared__ __align__(16) float lds[LDS_FLOATS];
    const int tid = threadIdx.x;

    // stage shared block (barrier happens inside run_group after x staging)
    {
        const f4x* src = (const f4x*)ws;
        f4x* dst = (f4x*)lds;
        #pragma unroll
        for (int c = 0; c < 17; ++c) {
            int i4 = c*256 + tid;
            if (i4 < STAGE_FLOATS/4) dst[i4] = src[i4];
        }
    }

    const int w = blockIdx.x;
    if (w < 64) {
        run_group<72>(x, lds, out, w >> 4, (w & 15)*16, 0, 256, 0);
    } else if (w < 128) {
        const int w2 = w - 64;
        run_group<144>(x, lds, out, w2 >> 4, (w2 & 15)*16, 18688, 256, 256);
    } else {
        const int w3 = w - 128;
        run_group<144>(x, lds, out, w3 >> 5, (w3 & 31)*16, 55808, 512, 512);
    }
}

extern "C" void kernel_launch(void* const* d_in, const int* in_sizes, int n_in,
                              void* d_out, int out_size, void* d_ws, size_t ws_size,
                              hipStream_t stream) {
    const float* x    = (const float*)d_in[0];
    const float* pe   = (const float*)d_in[1];
    const float* ct   = (const float*)d_in[2];
    const float* Wq   = (const float*)d_in[3];
    const float* bq   = (const float*)d_in[4];
    const float* Wo   = (const float*)d_in[5];
    const float* bo   = (const float*)d_in[6];
    const float* L1w  = (const float*)d_in[7];
    const float* b1   = (const float*)d_in[8];
    const float* L2w  = (const float*)d_in[9];
    const float* b2   = (const float*)d_in[10];
    const float* ln1w = (const float*)d_in[11];
    const float* ln1b = (const float*)d_in[12];
    const float* ln2w = (const float*)d_in[13];
    const float* ln2b = (const float*)d_in[14];
    float* out = (float*)d_out;
    float* ws  = (float*)d_ws;

    k_pre <<<150, 64, 0, stream>>>(pe, ct, Wq, bq, Wo, bo, L1w, b1, L2w, b2,
                                   ln1w, ln1b, ln2w, ln2b, ws);
    k_main<<<256, 256, 0, stream>>>(x, ws, out);
}

// Round 9
// 19.404 us; speedup vs baseline: 1.9648x; 1.0226x over previous
//
#include <hip/hip_runtime.h>
#include <math.h>

#define NPAR 130048
#define EPSF 1e-5f

typedef _Float16 hfp;
typedef _Float16 h2x __attribute__((ext_vector_type(2)));
typedef _Float16 h4x __attribute__((ext_vector_type(4)));
typedef float    f4x __attribute__((ext_vector_type(4)));

// ---- strides ----
#define BSTR  164      // beta row stride (f32)
#define VSTR2 172      // vposT row stride (halves)
#define ATSTR 172      // att row stride (halves)
#define WOSTR 76       // Wo / L1 / O / H1 row stride (halves)
#define L2STRH 108     // L2 / R row stride (halves)

// ---- ws layout (float offsets) — produced by k_pre, read directly (L2) by k_main ----
#define OFF_VPOST 0        // f16 [64][172]
#define OFF_WO    5504     // f16 [64][76]
#define OFF_L1    7936     // f16 [96][76]
#define OFF_L2    11584    // f16 [64][108]
#define OFF_BETA  15040    // f32 [4][164]
#define OFF_SM    15696    // f32 smalls
#define SM_CT   0
#define SM_BO   64
#define SM_B1   128
#define SM_B2   224
#define SM_LN1W 288
#define SM_LN1B 352
#define SM_LN2W 416
#define SM_LN2B 480
#define SM_ALPH 544
#define SM_GAM  548
#define SM_BOCT 576        // bo + ct precombined

// ---- LDS layout (float offsets) — block-private only ----
#define L_W    0           // f32 [16][L] packed (max 2304)
#define L_WB   2304        // f32 [16]
#define L_ATT  2320        // f16 [64][172] = 5504 floats
#define L_INVS 7824        // f32 [64]
#define L_O    7888        // f16 [16][76] = 608
#define L_H1   8496        // f16 [16][76] = 608
#define L_R    9104        // f16 [16][108] = 864
#define L_PRE  9968        // f32 [16][68] = 1088
#define L_RED  11056       // f32 [16]
#define LDS_FLOATS 11072   // 44,288 B

template<int C>
__device__ __forceinline__ float dppf(float x) {
    return __int_as_float(__builtin_amdgcn_update_dpp(0, __float_as_int(x), C, 0xf, 0xf, false));
}
__device__ __forceinline__ float rowsum16(float x) {
    x += dppf<0x128>(x); x += dppf<0x124>(x); x += dppf<0x122>(x); x += dppf<0x121>(x);
    return x;
}
__device__ __forceinline__ unsigned packh2(float a, float b) {
    union { h2x h; unsigned u; } cv;
    cv.h.x = (hfp)a; cv.h.y = (hfp)b;
    return cv.u;
}

// ===================== k_pre: build the packed block in ws (R8 + BOCT) =====================
__global__ __launch_bounds__(64) void k_pre(const float* __restrict__ pe,
                                            const float* __restrict__ ct,
                                            const float* __restrict__ W,
                                            const float* __restrict__ bq,
                                            const float* __restrict__ Wo,
                                            const float* __restrict__ bo,
                                            const float* __restrict__ L1w,
                                            const float* __restrict__ b1,
                                            const float* __restrict__ L2w,
                                            const float* __restrict__ b2,
                                            const float* __restrict__ ln1w,
                                            const float* __restrict__ ln1b,
                                            const float* __restrict__ ln2w,
                                            const float* __restrict__ ln2b,
                                            float* __restrict__ ws)
{
    const int j = blockIdx.x;
    const int o = threadIdx.x;
    hfp* wsh = (hfp*)ws;

    if (j < 145) {
        const float4* wq4 = (const float4*)(W + o*64);
        const float4* wk4 = (const float4*)(W + (64 + o)*64);
        const float4* wv4 = (const float4*)(W + (128 + o)*64);
        const float4* p4  = (const float4*)(pe + j*64);
        float sk = bq[64 + o], sv = bq[128 + o], sq = bq[o];
        #pragma unroll
        for (int e = 0; e < 16; ++e) {
            float4 k4 = wk4[e], v4 = wv4[e], q4 = wq4[e], pp = p4[e];
            float4 cc = ((const float4*)ct)[e];
            sk += k4.x*pp.x + k4.y*pp.y + k4.z*pp.z + k4.w*pp.w;
            sv += v4.x*pp.x + v4.y*pp.y + v4.z*pp.z + v4.w*pp.w;
            sq += q4.x*cc.x + q4.y*cc.y + q4.z*cc.z + q4.w*cc.w;
        }
        wsh[o*VSTR2 + j] = (hfp)sv;
        float r = sq * sk;
        #pragma unroll
        for (int off = 1; off < 16; off <<= 1) r += __shfl_xor(r, off);
        if ((o & 15) == 0) ws[OFF_BETA + (o >> 4)*BSTR + j] = r;
    } else if (j == 145) {
        const float4* wq4 = (const float4*)(W + o*64);
        const float4* wk4 = (const float4*)(W + (64 + o)*64);
        const float4* wv4 = (const float4*)(W + (128 + o)*64);
        float sq = bq[o], sk = bq[64 + o], sv = bq[128 + o], suk = 0.f, suv = 0.f;
        #pragma unroll
        for (int e = 0; e < 16; ++e) {
            float4 k4 = wk4[e], v4 = wv4[e], q4 = wq4[e];
            float4 cc = ((const float4*)ct)[e];
            sq += q4.x*cc.x + q4.y*cc.y + q4.z*cc.z + q4.w*cc.w;
            sk += k4.x*cc.x + k4.y*cc.y + k4.z*cc.z + k4.w*cc.w;
            sv += v4.x*cc.x + v4.y*cc.y + v4.z*cc.z + v4.w*cc.w;
            suk += k4.x + k4.y + k4.z + k4.w;
            suv += v4.x + v4.y + v4.z + v4.w;
        }
        wsh[o*VSTR2 + 156] = (hfp)sv;     // vcls
        wsh[o*VSTR2 + 157] = (hfp)suv;    // uv
        #pragma unroll
        for (int c = 145; c < 156; ++c) wsh[o*VSTR2 + c] = (hfp)0.f;
        wsh[o*VSTR2 + 158] = (hfp)0.f;
        wsh[o*VSTR2 + 159] = (hfp)0.f;
        float a = sq * suk, g = sq * sk;
        #pragma unroll
        for (int off = 1; off < 16; off <<= 1) {
            a += __shfl_xor(a, off);
            g += __shfl_xor(g, off);
        }
        if ((o & 15) == 0) {
            ws[OFF_SM + SM_ALPH + (o >> 4)] = a;
            ws[OFF_SM + SM_GAM  + (o >> 4)] = g;
        }
    } else if (j == 146) {
        ws[OFF_SM + SM_CT   + o] = ct[o];
        ws[OFF_SM + SM_BO   + o] = bo[o];
        ws[OFF_SM + SM_BOCT + o] = bo[o] + ct[o];
        ws[OFF_SM + SM_B2   + o] = b2[o];
        ws[OFF_SM + SM_LN1W + o] = ln1w[o];
        ws[OFF_SM + SM_LN1B + o] = ln1b[o];
        ws[OFF_SM + SM_LN2W + o] = ln2w[o];
        ws[OFF_SM + SM_LN2B + o] = ln2b[o];
        ws[OFF_SM + SM_B1   + o] = b1[o];
        if (o < 32) ws[OFF_SM + SM_B1 + 64 + o] = b1[64 + o];
    } else if (j == 147) {
        for (int idx = o; idx < 4096; idx += 64)
            wsh[OFF_WO*2 + (idx >> 6)*WOSTR + (idx & 63)] = (hfp)Wo[idx];
    } else if (j == 148) {
        for (int idx = o; idx < 6144; idx += 64)
            wsh[OFF_L1*2 + (idx >> 6)*WOSTR + (idx & 63)] = (hfp)L1w[idx];
    } else {
        for (int idx = o; idx < 6144; idx += 64) {
            int r = idx / 96, c = idx - r*96;
            wsh[OFF_L2*2 + r*L2STRH + c] = (hfp)L2w[idx];
        }
    }
}

// ===================== k_main: 4 waves per 16-seq group; weights direct from L2 =====================
template<int L>
__device__ __forceinline__ void run_group(const float* __restrict__ x,
                                          const float* __restrict__ ws,
                                          float* __restrict__ lds,
                                          float* __restrict__ out,
                                          int b, int k0, int start, int kno, int kgo)
{
    const int tid  = threadIdx.x;
    const int wave = tid >> 6;
    const int lane = tid & 63;
    const int e16  = lane & 15;
    const int g4   = (lane >> 4) * 4;
    const int c0   = e16 * 4;
    const hfp* wsh  = (const hfp*)ws;
    const hfp* ldsh = (const hfp*)lds;

    // ---------- phase 1: stage x -> LDS; wmax & maxbeta reduce; issue ALL weight prefetches ----------
    float wm = 0.f;
    {
        const f4x* src = (const f4x*)(x + (size_t)b*NPAR + start + (size_t)k0*L);
        f4x* dst = (f4x*)(lds + L_W);
        #pragma unroll
        for (int c = 0; c < (4*L + 255)/256; ++c) {
            int i4 = c*256 + tid;
            if (i4 < 4*L) {
                f4x v = src[i4];
                dst[i4] = v;
                wm = fmaxf(wm, fmaxf(fmaxf(fabsf(v.x), fabsf(v.y)), fmaxf(fabsf(v.z), fabsf(v.w))));
            }
        }
        if (tid < 16) {
            float bwv = x[(size_t)b*NPAR + start + (size_t)kno*L + k0 + tid];
            lds[L_WB + tid] = bwv;
            wm = fmaxf(wm, fabsf(bwv));
        }
    }

    // register prefetch of all per-lane weight fragments / scalars (L2-resident, read once)
    h4x vpf[10];
    #pragma unroll
    for (int kt = 0; kt < 10; ++kt)
        vpf[kt] = *(const h4x*)(wsh + (16*wave + e16)*VSTR2 + kt*16 + g4);
    h4x wof[4];
    #pragma unroll
    for (int kt = 0; kt < 4; ++kt)
        wof[kt] = *(const h4x*)(wsh + OFF_WO*2 + (16*wave + e16)*WOSTR + kt*16 + g4);
    h4x l1f[2][4];
    float b1v[2];
    #pragma unroll
    for (int u = 0; u < 2; ++u) {
        const int tt = wave + 4*u;
        if (tt < 6) {
            #pragma unroll
            for (int kt = 0; kt < 4; ++kt)
                l1f[u][kt] = *(const h4x*)(wsh + OFF_L1*2 + (16*tt + e16)*WOSTR + kt*16 + g4);
            b1v[u] = ws[OFF_SM + SM_B1 + 16*tt + e16];
        }
    }
    h4x l2f[6];
    #pragma unroll
    for (int kt = 0; kt < 6; ++kt)
        l2f[kt] = *(const h4x*)(wsh + OFF_L2*2 + (16*wave + e16)*L2STRH + kt*16 + g4);
    const int nw = 16*wave + e16;
    const float boct = ws[OFF_SM + SM_BOCT + nw];
    const float b2v  = ws[OFF_SM + SM_B2   + nw];
    const int hsm = (tid >> 2) & 3;
    const float alpha = ws[OFF_SM + SM_ALPH + hsm];
    const float gam   = ws[OFF_SM + SM_GAM  + hsm];
    const f4x ln1w4 = *(const f4x*)(ws + OFF_SM + SM_LN1W + c0);
    const f4x ln1b4 = *(const f4x*)(ws + OFF_SM + SM_LN1B + c0);
    const f4x ln2w4 = *(const f4x*)(ws + OFF_SM + SM_LN2W + c0);
    const f4x ln2b4 = *(const f4x*)(ws + OFF_SM + SM_LN2B + c0);

    // reductions into LDS (resolved by the barrier)
    {
        #pragma unroll
        for (int off = 1; off < 64; off <<= 1) wm = fmaxf(wm, __shfl_xor(wm, off));
        if (lane == 0) lds[L_RED + wave] = wm;
        float mb = -1e30f;
        for (int j = lane; j < 145; j += 64) mb = fmaxf(mb, ws[OFF_BETA + wave*BSTR + j]);
        #pragma unroll
        for (int off = 1; off < 64; off <<= 1) mb = fmaxf(mb, __shfl_xor(mb, off));
        if (lane == 0) lds[L_RED + 8 + wave] = mb;
    }
    __syncthreads();

    // ---------- phase 2: softmax (64 rows x 4 segments) ----------
    {
        const float wmax = fmaxf(fmaxf(lds[L_RED+0], lds[L_RED+1]),
                                 fmaxf(lds[L_RED+2], lds[L_RED+3]));
        const int r = tid >> 2;
        const int m = r >> 2, h = r & 3, q = tid & 3;
        const float mbh = lds[L_RED + 8 + h];
        const float M = fmaxf(0.25f*(fabsf(alpha)*wmax + mbh), 0.25f*gam);
        unsigned* arow32 = (unsigned*)(lds + L_ATT) + r*(ATSTR/2);
        const float* wr = lds + L_W + m*L;
        const float* br = ws + OFF_BETA + h*BSTR;
        float S = 0.f, WS = 0.f;
        #pragma unroll
        for (int t = 0; t < 10; ++t) {
            const int j0 = 16*t + 4*q;
            if (16*t + 15 < L || j0 + 3 < L) {
                f4x wv = *(const f4x*)(wr + j0);
                f4x bv = *(const f4x*)(br + j0);
                float p0 = __expf(fmaf(alpha, wv.x, bv.x)*0.25f - M);
                float p1 = __expf(fmaf(alpha, wv.y, bv.y)*0.25f - M);
                float p2 = __expf(fmaf(alpha, wv.z, bv.z)*0.25f - M);
                float p3 = __expf(fmaf(alpha, wv.w, bv.w)*0.25f - M);
                S  += (p0 + p1) + (p2 + p3);
                WS += (p0*wv.x + p1*wv.y) + (p2*wv.z + p3*wv.w);
                uint2 u; u.x = packh2(p0, p1); u.y = packh2(p2, p3);
                *(uint2*)(arow32 + (j0 >> 1)) = u;
            } else if (j0 <= L) {
                float pv4[4] = {0.f, 0.f, 0.f, 0.f};
                #pragma unroll
                for (int ee = 0; ee < 4; ++ee) {
                    int j = j0 + ee;
                    if (j <= L) {
                        float w = (j < L) ? wr[j] : lds[L_WB + m];
                        float p = __expf(fmaf(alpha, w, br[j])*0.25f - M);
                        S += p; WS += p*w; pv4[ee] = p;
                    }
                }
                uint2 u; u.x = packh2(pv4[0], pv4[1]); u.y = packh2(pv4[2], pv4[3]);
                *(uint2*)(arow32 + (j0 >> 1)) = u;
            } else if (j0 != 156) {
                uint2 z; z.x = 0u; z.y = 0u;
                *(uint2*)(arow32 + (j0 >> 1)) = z;
            }
        }
        S  += __shfl_xor(S, 1);  S  += __shfl_xor(S, 2);
        WS += __shfl_xor(WS, 1); WS += __shfl_xor(WS, 2);
        const float pc = __expf(0.25f*gam - M);
        S += pc;
        if (q == 0) {
            lds[L_INVS + r] = 1.f / S;
            arow32[78] = packh2(pc, WS);          // cols 156 (a0), 157 (wsum)
            arow32[79] = 0u;
        }
    }
    __syncthreads();

    // ---------- phase 3: V-step (wave = head; B-fragments prefetched) ----------
    {
        const hfp* atth = ldsh + L_ATT*2;
        const int hh = wave;
        f4x vacc = (f4x){0.f,0.f,0.f,0.f};
        #pragma unroll
        for (int kt = 0; kt < 10; ++kt) {
            h4x a = *(const h4x*)(atth + (e16*4 + hh)*ATSTR + kt*16 + g4);
            vacc = __builtin_amdgcn_mfma_f32_16x16x16f16(a, vpf[kt], vacc, 0, 0, 0);
        }
        hfp* Oh = (hfp*)(lds + L_O);
        #pragma unroll
        for (int rr = 0; rr < 4; ++rr) {
            float sc = lds[L_INVS + (g4 + rr)*4 + hh];
            Oh[(g4 + rr)*WOSTR + 16*hh + e16] = (hfp)(vacc[rr] * sc);
        }
    }
    __syncthreads();

    // ---------- phase 4: out-proj (wave = 16-col tile) ----------
    {
        const hfp* Oh = ldsh + L_O*2;
        f4x pacc = (f4x){0.f,0.f,0.f,0.f};
        #pragma unroll
        for (int kt = 0; kt < 4; ++kt) {
            h4x a = *(const h4x*)(Oh + e16*WOSTR + kt*16 + g4);
            pacc = __builtin_amdgcn_mfma_f32_16x16x16f16(a, wof[kt], pacc, 0, 0, 0);
        }
        #pragma unroll
        for (int rr = 0; rr < 4; ++rr)
            lds[L_PRE + (g4 + rr)*68 + nw] = pacc[rr] + boct;
    }
    __syncthreads();

    // ---------- phase 5: LN1 (wave owns 4 rows) ----------
    {
        const int m = wave*4 + (lane >> 4);
        f4x pv = *(const f4x*)(lds + L_PRE + m*68 + c0);
        float s = (pv.x + pv.y) + (pv.z + pv.w);
        float mu = rowsum16(s) * (1.f/64.f);
        f4x d; d.x = pv.x-mu; d.y = pv.y-mu; d.z = pv.z-mu; d.w = pv.w-mu;
        float v = (d.x*d.x + d.y*d.y) + (d.z*d.z + d.w*d.w);
        float rs = rsqrtf(rowsum16(v)*(1.f/64.f) + EPSF);
        h4x hv;
        hv.x = (hfp)(d.x*rs*ln1w4.x + ln1b4.x);
        hv.y = (hfp)(d.y*rs*ln1w4.y + ln1b4.y);
        hv.z = (hfp)(d.z*rs*ln1w4.z + ln1b4.z);
        hv.w = (hfp)(d.w*rs*ln1w4.w + ln1b4.w);
        *(h4x*)((hfp*)(lds + L_H1) + m*WOSTR + c0) = hv;
    }
    __syncthreads();

    // ---------- phase 6: FF1 + relu ----------
    {
        const hfp* H1h = ldsh + L_H1*2;
        h4x af[4];
        #pragma unroll
        for (int kt = 0; kt < 4; ++kt) af[kt] = *(const h4x*)(H1h + e16*WOSTR + kt*16 + g4);
        hfp* Rh = (hfp*)(lds + L_R);
        #pragma unroll
        for (int u = 0; u < 2; ++u) {
            const int tt = wave + 4*u;
            if (tt < 6) {
                f4x racc = (f4x){0.f,0.f,0.f,0.f};
                #pragma unroll
                for (int kt = 0; kt < 4; ++kt)
                    racc = __builtin_amdgcn_mfma_f32_16x16x16f16(af[kt], l1f[u][kt], racc, 0, 0, 0);
                const int n = 16*tt + e16;
                #pragma unroll
                for (int rr = 0; rr < 4; ++rr)
                    Rh[(g4 + rr)*L2STRH + n] = (hfp)fmaxf(racc[rr] + b1v[u], 0.f);
            }
        }
    }
    __syncthreads();

    // ---------- phase 7: FF2 ----------
    {
        const hfp* Rh2 = ldsh + L_R*2;
        f4x yacc = (f4x){0.f,0.f,0.f,0.f};
        #pragma unroll
        for (int kt = 0; kt < 6; ++kt) {
            h4x a = *(const h4x*)(Rh2 + e16*L2STRH + kt*16 + g4);
            yacc = __builtin_amdgcn_mfma_f32_16x16x16f16(a, l2f[kt], yacc, 0, 0, 0);
        }
        #pragma unroll
        for (int rr = 0; rr < 4; ++rr)
            lds[L_PRE + (g4 + rr)*68 + nw] = yacc[rr] + b2v;
    }
    __syncthreads();

    // ---------- phase 8: LN2 + residual(h1) + store ----------
    {
        const int m = wave*4 + (lane >> 4);
        f4x pv = *(const f4x*)(lds + L_PRE + m*68 + c0);
        h4x h1p = *(const h4x*)((const hfp*)(lds + L_H1) + m*WOSTR + c0);
        f4x tot;
        tot.x = pv.x + (float)h1p.x;
        tot.y = pv.y + (float)h1p.y;
        tot.z = pv.z + (float)h1p.z;
        tot.w = pv.w + (float)h1p.w;
        float s = (tot.x + tot.y) + (tot.z + tot.w);
        float mu = rowsum16(s) * (1.f/64.f);
        f4x d; d.x = tot.x-mu; d.y = tot.y-mu; d.z = tot.z-mu; d.w = tot.w-mu;
        float v = (d.x*d.x + d.y*d.y) + (d.z*d.z + d.w*d.w);
        float rs = rsqrtf(rowsum16(v)*(1.f/64.f) + EPSF);
        f4x y;
        y.x = d.x*rs*ln2w4.x + ln2b4.x;
        y.y = d.y*rs*ln2w4.y + ln2b4.y;
        y.z = d.z*rs*ln2w4.z + ln2b4.z;
        y.w = d.w*rs*ln2w4.w + ln2b4.w;
        float* ob = out + ((size_t)b*1024 + kgo + k0 + m)*128;
        *(f4x*)(ob + c0)      = y;
        *(f4x*)(ob + 64 + c0) = y;   // tile (1,1,2)
    }
}

__global__ __launch_bounds__(256, 1) void k_main(const float* __restrict__ x,
                                                 const float* __restrict__ ws,
                                                 float* __restrict__ out)
{
    __shared__ __align__(16) float lds[LDS_FLOATS];
    const int w = blockIdx.x;
    if (w < 64) {
        run_group<72>(x, ws, lds, out, w >> 4, (w & 15)*16, 0, 256, 0);
    } else if (w < 128) {
        const int w2 = w - 64;
        run_group<144>(x, ws, lds, out, w2 >> 4, (w2 & 15)*16, 18688, 256, 256);
    } else {
        const int w3 = w - 128;
        run_group<144>(x, ws, lds, out, w3 >> 5, (w3 & 31)*16, 55808, 512, 512);
    }
}

extern "C" void kernel_launch(void* const* d_in, const int* in_sizes, int n_in,
                              void* d_out, int out_size, void* d_ws, size_t ws_size,
                              hipStream_t stream) {
    const float* x    = (const float*)d_in[0];
    const float* pe   = (const float*)d_in[1];
    const float* ct   = (const float*)d_in[2];
    const float* Wq   = (const float*)d_in[3];
    const float* bq   = (const float*)d_in[4];
    const float* Wo   = (const float*)d_in[5];
    const float* bo   = (const float*)d_in[6];
    const float* L1w  = (const float*)d_in[7];
    const float* b1   = (const float*)d_in[8];
    const float* L2w  = (const float*)d_in[9];
    const float* b2   = (const float*)d_in[10];
    const float* ln1w = (const float*)d_in[11];
    const float* ln1b = (const float*)d_in[12];
    const float* ln2w = (const float*)d_in[13];
    const float* ln2b = (const float*)d_in[14];
    float* out = (float*)d_out;
    float* ws  = (float*)d_ws;

    k_pre <<<150, 64, 0, stream>>>(pe, ct, Wq, bq, Wo, bo, L1w, b1, L2w, b2,
                                   ln1w, ln1b, ln2w, ln2b, ws);
    k_main<<<256, 256, 0, stream>>>(x, ws, out);
}